// Round 9
// baseline (167.873 us; speedup 1.0000x reference)
//
#include <hip/hip_runtime.h>

// SelfAttention3D: B=4, C=HID=128, N=16^3=4096.
// R9: flash software pipeline (register prefetch of next K/V tile issued after
// the post-stage barrier -> global latency hidden behind compute) + LOG2E
// folded into Q at projection (exp2f(S) directly, no per-element mul).
//   projx  = convw+xt+proj fused (Q pre-scaled by log2e)
//   flash  = LDS-staged K/V w/ reg-prefetch pipeline, trunc-pack P, bf16 partials
//   mf     = merge slabs + block-local BN stats + BN + residual + store
// Workspace layout:
//   [0,4M)    Obuf bf16 [b][h][n]  (NSL==1 path only)
//   [4,8M)    Qb bf16 [b][n][h]    (pre-scaled by log2e)
//   [8,12M)   Kb bf16 [b][n][h]
//   [12,16M)  Vb bf16 [b][h][n]
//   [16M+128K,+512K) lpart f32 [NSL*4][4096]
//   [17M, 17M+NSL*4M) Opart bf16 [NSL*4][128][4096]
// Total need: 17M + NSL*4M  (NSL=1 path needs 17M only).

#define NV 4096
#define LOG2E 1.44269504088896340736f
#define EPSV 1e-5f

typedef float f32x4 __attribute__((ext_vector_type(4)));
typedef short bf16x8 __attribute__((ext_vector_type(8)));
typedef unsigned short u16x4 __attribute__((ext_vector_type(4)));
typedef unsigned short u16x8 __attribute__((ext_vector_type(8)));
typedef unsigned int u32x2 __attribute__((ext_vector_type(2)));

static __device__ __forceinline__ unsigned short f2bf(float f) {
    union { float f; unsigned u; } v; v.f = f;
    unsigned r = v.u + 0x7FFFu + ((v.u >> 16) & 1u);   // RNE
    return (unsigned short)(r >> 16);
}
static __device__ __forceinline__ float bf2f(unsigned short u) {
    union { unsigned u; float f; } v; v.u = ((unsigned)u) << 16; return v.f;
}
static __device__ __forceinline__ unsigned fbits(float f) {
    union { float f; unsigned u; } v; v.f = f; return v.u;
}

// ---------------- fused x-transpose + W-convert + QKV projection ----------------
// grid 256 = b(4) x nchunk(64); block 256 = 4 waves x 16 voxels.
__global__ __launch_bounds__(256) void projx_kernel(
    const float* __restrict__ x,
    const float* __restrict__ Wq, const float* __restrict__ Wk,
    const float* __restrict__ Wv,
    const float* __restrict__ bq, const float* __restrict__ bk,
    const float* __restrict__ bv,
    unsigned short* __restrict__ Qb, unsigned short* __restrict__ Kb,
    unsigned short* __restrict__ Vb)
{
    __shared__ unsigned short xt[64 * 136];
    __shared__ unsigned short Wl[128 * 136];
    __shared__ unsigned short vtile[128 * 66];
    const int b = blockIdx.x >> 6, n0 = (blockIdx.x & 63) << 6;
    const int t = threadIdx.x, w = t >> 6, lane = t & 63;
    const int quad = lane >> 4, l16 = lane & 15;

    // transpose x[b][c][n0+il] -> xt[il][c] (bf16)
    #pragma unroll
    for (int it = 0; it < 32; ++it) {
        const int e = it * 256 + t;
        const int c = e >> 6, il = e & 63;
        xt[il * 136 + c] = f2bf(x[(((b << 7) + c) << 12) + n0 + il]);
    }
    __syncthreads();

    bf16x8 af[4];
    {
        const int il = (w << 4) + l16;
        #pragma unroll
        for (int ck = 0; ck < 4; ++ck)
            af[ck] = *(const bf16x8*)(xt + il * 136 + (ck << 5) + (quad << 3));
    }
    const int vb = n0 + (w << 4);
    const float* Ws[3] = {Wq, Wk, Wv};
    const float* bs[3] = {bq, bk, bv};

    for (int m = 0; m < 3; ++m) {
        __syncthreads();
        #pragma unroll
        for (int it = 0; it < 16; ++it) {
            const int idx = it * 1024 + (t << 2);
            const float4 wv4 = *(const float4*)(Ws[m] + idx);
            const int h = idx >> 7, c = idx & 127;
            u16x4 pk;
            pk[0] = f2bf(wv4.x); pk[1] = f2bf(wv4.y);
            pk[2] = f2bf(wv4.z); pk[3] = f2bf(wv4.w);
            *(u16x4*)(Wl + h * 136 + c) = pk;
        }
        __syncthreads();

        const float* bias = bs[m];
        unsigned short* dst = (m == 0) ? Qb : Kb;
        #pragma unroll
        for (int s = 0; s < 8; ++s) {
            const int h = (s << 4) + l16;
            f32x4 acc = {0.f, 0.f, 0.f, 0.f};
            #pragma unroll
            for (int ck = 0; ck < 4; ++ck) {
                const bf16x8 wf = *(const bf16x8*)(Wl + h * 136 + (ck << 5) + (quad << 3));
                acc = __builtin_amdgcn_mfma_f32_16x16x32_bf16(af[ck], wf, acc, 0, 0, 0);
            }
            const float bval = bias[h];
            if (m == 2) {
                #pragma unroll
                for (int r = 0; r < 4; ++r)
                    vtile[h * 66 + (w << 4) + (quad << 2) + r] = f2bf(acc[r] + bval);
            } else {
                #pragma unroll
                for (int r = 0; r < 4; ++r) {
                    float val = acc[r] + bval;
                    if (m == 0) val *= LOG2E;          // fold softmax exp2 scale into Q
                    const int n = vb + (quad << 2) + r;
                    dst[(((b << 12) + n) << 7) + h] = f2bf(val);
                }
            }
        }
    }
    __syncthreads();
    #pragma unroll
    for (int it = 0; it < 32; ++it) {
        const int e = it * 256 + t;
        const int h = e >> 6, il = e & 63;
        Vb[(((b << 7) + h) << 12) + n0 + il] = vtile[h * 66 + il];
    }
}

// ---------------- flash attention (reg-prefetch pipelined) ----------------
// grid NSL*128 = sl(NSL) x b(4) x ic(32); block 256 = 4 waves; wave owns 32 i-rows.
// Per tile: barrier -> ds_write(prefetched regs) -> barrier -> issue next tile's
// global loads -> compute (S^T=K.Q^T, exp2, trunc-pack P, O^T+=V.P^T).
template<int NSL>
__global__ __launch_bounds__(256, 2) void flash_kernel(
    const unsigned short* __restrict__ Qb,
    const unsigned short* __restrict__ Kb,
    const unsigned short* __restrict__ Vb,
    unsigned short* __restrict__ Opart, float* __restrict__ lpart,
    unsigned short* __restrict__ Obuf)
{
    __shared__ unsigned short Kt[64 * 128];           // [j][h], 16B-granule XOR-swizzle
    __shared__ unsigned short Vt[128 * 64];           // [h][j], 16B-granule XOR-swizzle
    __shared__ unsigned short pA[4][32 * 72];         // per-wave P [i=32][j=64], stride 72
    const int bid = blockIdx.x;
    const int sl = bid >> 7, b = (bid >> 5) & 3, ic = bid & 31;
    const int t = threadIdx.x, w = t >> 6, lane = t & 63;
    const int quad = lane >> 4, l16 = lane & 15;
    const int iw = (ic << 7) + (w << 5);
    const int jbase = sl * (NV / NSL);
    unsigned short* pAw = pA[w];

    const int ktg = t & 15, ktj = t >> 4;
    const int vtg = t & 7,  vth = t >> 3;
    const int kswz = (ktg ^ ktj) << 3;
    const int vswz = (vtg ^ (vth & 7)) << 3;

    bf16x8 qf[2][4];
    #pragma unroll
    for (int half = 0; half < 2; ++half) {
        const unsigned short* qp =
            Qb + (((b << 12) + iw + (half << 4) + l16) << 7) + (quad << 3);
        #pragma unroll
        for (int ck = 0; ck < 4; ++ck) qf[half][ck] = *(const bf16x8*)(qp + (ck << 5));
    }
    f32x4 Oacc[2][8];
    #pragma unroll
    for (int half = 0; half < 2; ++half)
        #pragma unroll
        for (int s = 0; s < 8; ++s) Oacc[half][s] = (f32x4){0.f, 0.f, 0.f, 0.f};
    float lsum0 = 0.f, lsum1 = 0.f;

    const unsigned short* Kbb = Kb + ((long)b << 19);
    const unsigned short* Vbb = Vb + ((long)b << 19);
    const int T = (NV / NSL) >> 6;

    // prologue: prefetch tile 0 into regs
    bf16x8 sk[4], sv[4];
    #pragma unroll
    for (int r = 0; r < 4; ++r)
        sk[r] = *(const bf16x8*)(Kbb + ((jbase + (r << 4) + ktj) << 7) + (ktg << 3));
    #pragma unroll
    for (int r = 0; r < 4; ++r)
        sv[r] = *(const bf16x8*)(Vbb + (((r << 5) + vth) << 12) + jbase + (vtg << 3));

    for (int t8 = 0; t8 < T; ++t8) {
        const int j0 = jbase + (t8 << 6);

        __syncthreads();                              // prev tile's LDS reads done
        #pragma unroll
        for (int r = 0; r < 4; ++r)
            *(bf16x8*)(Kt + (((r << 4) + ktj) << 7) + kswz) = sk[r];
        #pragma unroll
        for (int r = 0; r < 4; ++r)
            *(bf16x8*)(Vt + (((r << 5) + vth) << 6) + vswz) = sv[r];
        __syncthreads();                              // tile visible

        if (t8 + 1 < T) {                             // issue next tile's loads now;
            const int j1 = j0 + 64;                   // they drain behind this tile's compute
            #pragma unroll
            for (int r = 0; r < 4; ++r)
                sk[r] = *(const bf16x8*)(Kbb + ((j1 + (r << 4) + ktj) << 7) + (ktg << 3));
            #pragma unroll
            for (int r = 0; r < 4; ++r)
                sv[r] = *(const bf16x8*)(Vbb + (((r << 5) + vth) << 12) + j1 + (vtg << 3));
        }

        // ---- S^T = K·Q^T per 16-j subtile (Q pre-scaled by log2e) ----
        #pragma unroll
        for (int js = 0; js < 4; ++js) {
            bf16x8 kf[4];
            const int krow = ((js << 4) + l16) << 7;
            #pragma unroll
            for (int ck = 0; ck < 4; ++ck)
                kf[ck] = *(const bf16x8*)(Kt + krow + ((((ck << 2) + quad) ^ l16) << 3));
            f32x4 a0 = {0.f, 0.f, 0.f, 0.f}, a1 = {0.f, 0.f, 0.f, 0.f};
            #pragma unroll
            for (int ck = 0; ck < 4; ++ck) {
                a0 = __builtin_amdgcn_mfma_f32_16x16x32_bf16(kf[ck], qf[0][ck], a0, 0, 0, 0);
                a1 = __builtin_amdgcn_mfma_f32_16x16x32_bf16(kf[ck], qf[1][ck], a1, 0, 0, 0);
            }
            f32x4 e0, e1;
            #pragma unroll
            for (int r = 0; r < 4; ++r) {
                e0[r] = exp2f(a0[r]);
                e1[r] = exp2f(a1[r]);
            }
            lsum0 += (e0[0] + e0[1]) + (e0[2] + e0[3]);
            lsum1 += (e1[0] + e1[1]) + (e1[2] + e1[3]);
            u32x2 pk0, pk1;
            pk0[0] = __builtin_amdgcn_perm(fbits(e0[1]), fbits(e0[0]), 0x07060302u);
            pk0[1] = __builtin_amdgcn_perm(fbits(e0[3]), fbits(e0[2]), 0x07060302u);
            pk1[0] = __builtin_amdgcn_perm(fbits(e1[1]), fbits(e1[0]), 0x07060302u);
            pk1[1] = __builtin_amdgcn_perm(fbits(e1[3]), fbits(e1[2]), 0x07060302u);
            const int jc = (js << 4) + (quad << 2);
            *(u32x2*)(pAw + l16 * 72 + jc)        = pk0;
            *(u32x2*)(pAw + (16 + l16) * 72 + jc) = pk1;
        }
        // ---- O^T += V·P^T ----
        bf16x8 pf[2][2];
        #pragma unroll
        for (int half = 0; half < 2; ++half)
            #pragma unroll
            for (int kh = 0; kh < 2; ++kh)
                pf[half][kh] = *(const bf16x8*)(pAw + ((half << 4) + l16) * 72 +
                                                (kh << 5) + (quad << 3));
        #pragma unroll
        for (int s = 0; s < 8; ++s) {
            const int vrow = ((s << 4) + l16) << 6;
            const bf16x8 v0 = *(const bf16x8*)(Vt + vrow + ((quad ^ (l16 & 7)) << 3));
            const bf16x8 v1 = *(const bf16x8*)(Vt + vrow + (((4 + quad) ^ (l16 & 7)) << 3));
            Oacc[0][s] = __builtin_amdgcn_mfma_f32_16x16x32_bf16(v0, pf[0][0], Oacc[0][s], 0, 0, 0);
            Oacc[0][s] = __builtin_amdgcn_mfma_f32_16x16x32_bf16(v1, pf[0][1], Oacc[0][s], 0, 0, 0);
            Oacc[1][s] = __builtin_amdgcn_mfma_f32_16x16x32_bf16(v0, pf[1][0], Oacc[1][s], 0, 0, 0);
            Oacc[1][s] = __builtin_amdgcn_mfma_f32_16x16x32_bf16(v1, pf[1][1], Oacc[1][s], 0, 0, 0);
        }
    }

    float l0 = lsum0; l0 += __shfl_xor(l0, 16); l0 += __shfl_xor(l0, 32);
    float l1 = lsum1; l1 += __shfl_xor(l1, 16); l1 += __shfl_xor(l1, 32);

    if (NSL == 1) {
        const float rl0 = 1.f / l0, rl1 = 1.f / l1;
        #pragma unroll
        for (int s = 0; s < 8; ++s)
            #pragma unroll
            for (int r = 0; r < 4; ++r) {
                const int h = (s << 4) + (quad << 2) + r;
                Obuf[(((b << 7) + h) << 12) + iw + l16]      = f2bf(Oacc[0][s][r] * rl0);
                Obuf[(((b << 7) + h) << 12) + iw + 16 + l16] = f2bf(Oacc[1][s][r] * rl1);
            }
    } else {
        const int slb = (sl << 2) + b;
        if (quad == 0) {
            lpart[(slb << 12) + iw + l16]      = l0;
            lpart[(slb << 12) + iw + 16 + l16] = l1;
        }
        unsigned short* Ob = Opart + ((long)slb << 19);
        #pragma unroll
        for (int half = 0; half < 2; ++half)
            #pragma unroll
            for (int s = 0; s < 8; ++s)
                #pragma unroll
                for (int r = 0; r < 4; ++r) {
                    const int h = (s << 4) + (quad << 2) + r;
                    Ob[(h << 12) + iw + (half << 4) + l16] = f2bf(Oacc[half][s][r]);
                }
    }
}

// ---------------- merge + BN stats + final, one block per channel ----------------
template<int NSL>
__global__ __launch_bounds__(1024) void mf_kernel(
    const unsigned short* __restrict__ Opart, const float* __restrict__ lpart,
    const float* __restrict__ x, const float* __restrict__ bnw,
    const float* __restrict__ bnb, const float* __restrict__ gammap,
    float* __restrict__ out)
{
    const int h = blockIdx.x;
    const int t = threadIdx.x;
    const int b = t >> 8;
    const int i0 = (t & 255) << 4;

    float A[16], L[16];
    #pragma unroll
    for (int k = 0; k < 16; ++k) { A[k] = 0.f; L[k] = 0.f; }
    #pragma unroll
    for (int sl = 0; sl < NSL; ++sl) {
        const int slb = (sl << 2) + b;
        const u16x8 u0 = *(const u16x8*)(Opart + ((long)slb << 19) + ((long)h << 12) + i0);
        const u16x8 u1 = *(const u16x8*)(Opart + ((long)slb << 19) + ((long)h << 12) + i0 + 8);
        const float* lp = lpart + (slb << 12) + i0;
        #pragma unroll
        for (int k = 0; k < 8; ++k) { A[k] += bf2f(u0[k]); A[8 + k] += bf2f(u1[k]); }
        #pragma unroll
        for (int k = 0; k < 4; ++k) {
            const float4 lv = *(const float4*)(lp + (k << 2));
            L[(k << 2) + 0] += lv.x; L[(k << 2) + 1] += lv.y;
            L[(k << 2) + 2] += lv.z; L[(k << 2) + 3] += lv.w;
        }
    }
    float o[16], s = 0.f, ss = 0.f;
    #pragma unroll
    for (int k = 0; k < 16; ++k) {
        o[k] = A[k] / L[k];
        s += o[k]; ss += o[k] * o[k];
    }
    #pragma unroll
    for (int off = 32; off; off >>= 1) {
        s  += __shfl_down(s, off);
        ss += __shfl_down(ss, off);
    }
    __shared__ float rs[16], rss[16], fin[2];
    const int wid = t >> 6;
    if ((t & 63) == 0) { rs[wid] = s; rss[wid] = ss; }
    __syncthreads();
    if (t == 0) {
        float s2 = 0.f, ss2 = 0.f;
        #pragma unroll
        for (int k = 0; k < 16; ++k) { s2 += rs[k]; ss2 += rss[k]; }
        fin[0] = s2; fin[1] = ss2;
    }
    __syncthreads();
    const float inv = 1.f / 16384.f;
    const float mean = fin[0] * inv;
    const float var  = fin[1] * inv - mean * mean;
    const float g = gammap[0];
    const float scale = bnw[h] * rsqrtf(var + EPSV);
    const float a  = g * scale;
    const float bb = g * (bnb[h] - mean * scale);

    const float* xp = x + (((b << 7) + h) << 12) + i0;
    float* op = out + (((b << 7) + h) << 12) + i0;
    #pragma unroll
    for (int k = 0; k < 4; ++k) {
        const float4 xv = *(const float4*)(xp + (k << 2));
        float4 r;
        r.x = o[(k << 2) + 0] * a + bb + xv.x;
        r.y = o[(k << 2) + 1] * a + bb + xv.y;
        r.z = o[(k << 2) + 2] * a + bb + xv.z;
        r.w = o[(k << 2) + 3] * a + bb + xv.w;
        *(float4*)(op + (k << 2)) = r;
    }
}

// NSL==1 variant: Obuf already normalized bf16
__global__ __launch_bounds__(1024) void mf1_kernel(
    const unsigned short* __restrict__ Obuf,
    const float* __restrict__ x, const float* __restrict__ bnw,
    const float* __restrict__ bnb, const float* __restrict__ gammap,
    float* __restrict__ out)
{
    const int h = blockIdx.x;
    const int t = threadIdx.x;
    const int b = t >> 8;
    const int i0 = (t & 255) << 4;
    const u16x8 u0 = *(const u16x8*)(Obuf + (((b << 7) + h) << 12) + i0);
    const u16x8 u1 = *(const u16x8*)(Obuf + (((b << 7) + h) << 12) + i0 + 8);
    float o[16], s = 0.f, ss = 0.f;
    #pragma unroll
    for (int k = 0; k < 8; ++k) { o[k] = bf2f(u0[k]); o[8 + k] = bf2f(u1[k]); }
    #pragma unroll
    for (int k = 0; k < 16; ++k) { s += o[k]; ss += o[k] * o[k]; }
    #pragma unroll
    for (int off = 32; off; off >>= 1) {
        s  += __shfl_down(s, off);
        ss += __shfl_down(ss, off);
    }
    __shared__ float rs[16], rss[16], fin[2];
    const int wid = t >> 6;
    if ((t & 63) == 0) { rs[wid] = s; rss[wid] = ss; }
    __syncthreads();
    if (t == 0) {
        float s2 = 0.f, ss2 = 0.f;
        #pragma unroll
        for (int k = 0; k < 16; ++k) { s2 += rs[k]; ss2 += rss[k]; }
        fin[0] = s2; fin[1] = ss2;
    }
    __syncthreads();
    const float inv = 1.f / 16384.f;
    const float mean = fin[0] * inv;
    const float var  = fin[1] * inv - mean * mean;
    const float g = gammap[0];
    const float scale = bnw[h] * rsqrtf(var + EPSV);
    const float a  = g * scale;
    const float bb = g * (bnb[h] - mean * scale);
    const float* xp = x + (((b << 7) + h) << 12) + i0;
    float* op = out + (((b << 7) + h) << 12) + i0;
    #pragma unroll
    for (int k = 0; k < 4; ++k) {
        const float4 xv = *(const float4*)(xp + (k << 2));
        float4 r;
        r.x = o[(k << 2) + 0] * a + bb + xv.x;
        r.y = o[(k << 2) + 1] * a + bb + xv.y;
        r.z = o[(k << 2) + 2] * a + bb + xv.z;
        r.w = o[(k << 2) + 3] * a + bb + xv.w;
        *(float4*)(op + (k << 2)) = r;
    }
}

extern "C" void kernel_launch(void* const* d_in, const int* in_sizes, int n_in,
                              void* d_out, int out_size, void* d_ws, size_t ws_size,
                              hipStream_t stream) {
    const float* x   = (const float*)d_in[0];
    const float* Wq  = (const float*)d_in[1];
    const float* bq  = (const float*)d_in[2];
    const float* Wk  = (const float*)d_in[3];
    const float* bk  = (const float*)d_in[4];
    const float* Wv  = (const float*)d_in[5];
    const float* bv  = (const float*)d_in[6];
    const float* bnw = (const float*)d_in[7];
    const float* bnb = (const float*)d_in[8];
    const float* gam = (const float*)d_in[9];
    float* out = (float*)d_out;

    char* ws = (char*)d_ws;
    unsigned short* Obuf = (unsigned short*)(ws);
    unsigned short* Qb   = (unsigned short*)(ws + (4u  << 20));
    unsigned short* Kb   = (unsigned short*)(ws + (8u  << 20));
    unsigned short* Vb   = (unsigned short*)(ws + (12u << 20));
    float*          lpart = (float*)(ws + (16u << 20) + (128u << 10));
    unsigned short* Opart = (unsigned short*)(ws + (17u << 20));

    int nsl = 1;
    if      (ws_size >= (17ull << 20) + (32ull << 20)) nsl = 8;
    else if (ws_size >= (17ull << 20) + (16ull << 20)) nsl = 4;
    else if (ws_size >= (17ull << 20) + (8ull  << 20)) nsl = 2;

    projx_kernel<<<256, 256, 0, stream>>>(x, Wq, Wk, Wv, bq, bk, bv, Qb, Kb, Vb);
    if (nsl == 8) {
        flash_kernel<8><<<1024, 256, 0, stream>>>(Qb, Kb, Vb, Opart, lpart, Obuf);
        mf_kernel<8><<<128, 1024, 0, stream>>>(Opart, lpart, x, bnw, bnb, gam, out);
    } else if (nsl == 4) {
        flash_kernel<4><<<512, 256, 0, stream>>>(Qb, Kb, Vb, Opart, lpart, Obuf);
        mf_kernel<4><<<128, 1024, 0, stream>>>(Opart, lpart, x, bnw, bnb, gam, out);
    } else if (nsl == 2) {
        flash_kernel<2><<<256, 256, 0, stream>>>(Qb, Kb, Vb, Opart, lpart, Obuf);
        mf_kernel<2><<<128, 1024, 0, stream>>>(Opart, lpart, x, bnw, bnb, gam, out);
    } else {
        flash_kernel<1><<<128, 256, 0, stream>>>(Qb, Kb, Vb, Opart, lpart, Obuf);
        mf1_kernel<<<128, 1024, 0, stream>>>(Obuf, x, bnw, bnb, gam, out);
    }
}

// Round 10
// 149.223 us; speedup vs baseline: 1.1250x; 1.1250x over previous
//
#include <hip/hip_runtime.h>

// SelfAttention3D: B=4, C=HID=128, N=16^3=4096.
// R10: flash uses raw v_exp_f32 (__builtin_amdgcn_exp2f; OCML exp2f's guard
// code was ~3x the VALU). projx de-serialized: one m per block (grid 768),
// vtile aliases dead xt. mf unchanged.
// Workspace layout:
//   [0,4M)    Obuf bf16 [b][h][n]  (NSL==1 path only)
//   [4,8M)    Qb bf16 [b][n][h]    (pre-scaled by log2e)
//   [8,12M)   Kb bf16 [b][n][h]
//   [12,16M)  Vb bf16 [b][h][n]
//   [16M+128K,+512K) lpart f32 [NSL*4][4096]
//   [17M, 17M+NSL*4M) Opart bf16 [NSL*4][128][4096]
// Total need: 17M + NSL*4M  (NSL=1 path needs 17M only).

#define NV 4096
#define LOG2E 1.44269504088896340736f
#define EPSV 1e-5f

typedef float f32x4 __attribute__((ext_vector_type(4)));
typedef short bf16x8 __attribute__((ext_vector_type(8)));
typedef unsigned short u16x4 __attribute__((ext_vector_type(4)));
typedef unsigned short u16x8 __attribute__((ext_vector_type(8)));
typedef unsigned int u32x2 __attribute__((ext_vector_type(2)));

static __device__ __forceinline__ unsigned short f2bf(float f) {
    union { float f; unsigned u; } v; v.f = f;
    unsigned r = v.u + 0x7FFFu + ((v.u >> 16) & 1u);   // RNE
    return (unsigned short)(r >> 16);
}
static __device__ __forceinline__ float bf2f(unsigned short u) {
    union { unsigned u; float f; } v; v.u = ((unsigned)u) << 16; return v.f;
}
static __device__ __forceinline__ unsigned fbits(float f) {
    union { float f; unsigned u; } v; v.f = f; return v.u;
}

// ---------------- fused x-transpose + W-convert + QKV projection ----------------
// grid 768 = m(3) x b(4) x nchunk(64); block 256 = 4 waves x 16 voxels.
// Each block handles ONE m: no serial W stages. x transposed redundantly (3x).
// LDS: xt [64][136] (17.4K, reused as vtile for m==2) + Wl [128][136] (34.8K).
__global__ __launch_bounds__(256) void projx_kernel(
    const float* __restrict__ x,
    const float* __restrict__ Wq, const float* __restrict__ Wk,
    const float* __restrict__ Wv,
    const float* __restrict__ bq, const float* __restrict__ bk,
    const float* __restrict__ bv,
    unsigned short* __restrict__ Qb, unsigned short* __restrict__ Kb,
    unsigned short* __restrict__ Vb)
{
    __shared__ unsigned short xt[64 * 136];           // -> vtile (stride 66) for m==2
    __shared__ unsigned short Wl[128 * 136];
    const int bid = blockIdx.x;
    const int m = bid >> 8, b = (bid >> 6) & 3, n0 = (bid & 63) << 6;
    const int t = threadIdx.x, w = t >> 6, lane = t & 63;
    const int quad = lane >> 4, l16 = lane & 15;

    const float* Wm = (m == 0) ? Wq : ((m == 1) ? Wk : Wv);
    const float* bias = (m == 0) ? bq : ((m == 1) ? bk : bv);

    // transpose x[b][c][n0+il] -> xt[il][c] (bf16)
    #pragma unroll
    for (int it = 0; it < 32; ++it) {
        const int e = it * 256 + t;
        const int c = e >> 6, il = e & 63;
        xt[il * 136 + c] = f2bf(x[(((b << 7) + c) << 12) + n0 + il]);
    }
    // stage W_m f32 -> Wl bf16 [h][c] (same barrier covers both)
    #pragma unroll
    for (int it = 0; it < 16; ++it) {
        const int idx = it * 1024 + (t << 2);
        const float4 wv4 = *(const float4*)(Wm + idx);
        const int h = idx >> 7, c = idx & 127;
        u16x4 pk;
        pk[0] = f2bf(wv4.x); pk[1] = f2bf(wv4.y);
        pk[2] = f2bf(wv4.z); pk[3] = f2bf(wv4.w);
        *(u16x4*)(Wl + h * 136 + c) = pk;
    }
    __syncthreads();

    bf16x8 af[4];
    {
        const int il = (w << 4) + l16;
        #pragma unroll
        for (int ck = 0; ck < 4; ++ck)
            af[ck] = *(const bf16x8*)(xt + il * 136 + (ck << 5) + (quad << 3));
    }
    if (m == 2) __syncthreads();                      // all af reads done before vtile reuse

    const int vb = n0 + (w << 4);
    unsigned short* dst = (m == 0) ? Qb : Kb;
    #pragma unroll
    for (int s = 0; s < 8; ++s) {
        const int h = (s << 4) + l16;
        f32x4 acc = {0.f, 0.f, 0.f, 0.f};
        #pragma unroll
        for (int ck = 0; ck < 4; ++ck) {
            const bf16x8 wf = *(const bf16x8*)(Wl + h * 136 + (ck << 5) + (quad << 3));
            acc = __builtin_amdgcn_mfma_f32_16x16x32_bf16(af[ck], wf, acc, 0, 0, 0);
        }
        const float bval = bias[h];
        if (m == 2) {
            #pragma unroll
            for (int r = 0; r < 4; ++r)
                xt[h * 66 + (w << 4) + (quad << 2) + r] = f2bf(acc[r] + bval);
        } else {
            #pragma unroll
            for (int r = 0; r < 4; ++r) {
                float val = acc[r] + bval;
                if (m == 0) val *= LOG2E;             // fold softmax exp2 scale into Q
                const int n = vb + (quad << 2) + r;
                dst[(((b << 12) + n) << 7) + h] = f2bf(val);
            }
        }
    }
    if (m == 2) {
        __syncthreads();
        #pragma unroll
        for (int it = 0; it < 32; ++it) {
            const int e = it * 256 + t;
            const int h = e >> 6, il = e & 63;
            Vb[(((b << 7) + h) << 12) + n0 + il] = xt[h * 66 + il];
        }
    }
}

// ---------------- flash attention (reg-prefetch pipelined, raw v_exp) ----------------
// grid NSL*128 = sl(NSL) x b(4) x ic(32); block 256 = 4 waves; wave owns 32 i-rows.
template<int NSL>
__global__ __launch_bounds__(256, 2) void flash_kernel(
    const unsigned short* __restrict__ Qb,
    const unsigned short* __restrict__ Kb,
    const unsigned short* __restrict__ Vb,
    unsigned short* __restrict__ Opart, float* __restrict__ lpart,
    unsigned short* __restrict__ Obuf)
{
    __shared__ unsigned short Kt[64 * 128];           // [j][h], 16B-granule XOR-swizzle
    __shared__ unsigned short Vt[128 * 64];           // [h][j], 16B-granule XOR-swizzle
    __shared__ unsigned short pA[4][32 * 72];         // per-wave P [i=32][j=64], stride 72
    const int bid = blockIdx.x;
    const int sl = bid >> 7, b = (bid >> 5) & 3, ic = bid & 31;
    const int t = threadIdx.x, w = t >> 6, lane = t & 63;
    const int quad = lane >> 4, l16 = lane & 15;
    const int iw = (ic << 7) + (w << 5);
    const int jbase = sl * (NV / NSL);
    unsigned short* pAw = pA[w];

    const int ktg = t & 15, ktj = t >> 4;
    const int vtg = t & 7,  vth = t >> 3;
    const int kswz = (ktg ^ ktj) << 3;
    const int vswz = (vtg ^ (vth & 7)) << 3;

    bf16x8 qf[2][4];
    #pragma unroll
    for (int half = 0; half < 2; ++half) {
        const unsigned short* qp =
            Qb + (((b << 12) + iw + (half << 4) + l16) << 7) + (quad << 3);
        #pragma unroll
        for (int ck = 0; ck < 4; ++ck) qf[half][ck] = *(const bf16x8*)(qp + (ck << 5));
    }
    f32x4 Oacc[2][8];
    #pragma unroll
    for (int half = 0; half < 2; ++half)
        #pragma unroll
        for (int s = 0; s < 8; ++s) Oacc[half][s] = (f32x4){0.f, 0.f, 0.f, 0.f};
    float lsum0 = 0.f, lsum1 = 0.f;

    const unsigned short* Kbb = Kb + ((long)b << 19);
    const unsigned short* Vbb = Vb + ((long)b << 19);
    const int T = (NV / NSL) >> 6;

    // prologue: prefetch tile 0 into regs
    bf16x8 sk[4], sv[4];
    #pragma unroll
    for (int r = 0; r < 4; ++r)
        sk[r] = *(const bf16x8*)(Kbb + ((jbase + (r << 4) + ktj) << 7) + (ktg << 3));
    #pragma unroll
    for (int r = 0; r < 4; ++r)
        sv[r] = *(const bf16x8*)(Vbb + (((r << 5) + vth) << 12) + jbase + (vtg << 3));

    for (int t8 = 0; t8 < T; ++t8) {
        const int j0 = jbase + (t8 << 6);

        __syncthreads();                              // prev tile's LDS reads done
        #pragma unroll
        for (int r = 0; r < 4; ++r)
            *(bf16x8*)(Kt + (((r << 4) + ktj) << 7) + kswz) = sk[r];
        #pragma unroll
        for (int r = 0; r < 4; ++r)
            *(bf16x8*)(Vt + (((r << 5) + vth) << 6) + vswz) = sv[r];
        __syncthreads();                              // tile visible

        if (t8 + 1 < T) {                             // issue next tile's loads now
            const int j1 = j0 + 64;
            #pragma unroll
            for (int r = 0; r < 4; ++r)
                sk[r] = *(const bf16x8*)(Kbb + ((j1 + (r << 4) + ktj) << 7) + (ktg << 3));
            #pragma unroll
            for (int r = 0; r < 4; ++r)
                sv[r] = *(const bf16x8*)(Vbb + (((r << 5) + vth) << 12) + j1 + (vtg << 3));
        }

        // ---- S^T = K·Q^T per 16-j subtile (Q pre-scaled by log2e) ----
        #pragma unroll
        for (int js = 0; js < 4; ++js) {
            bf16x8 kf[4];
            const int krow = ((js << 4) + l16) << 7;
            #pragma unroll
            for (int ck = 0; ck < 4; ++ck)
                kf[ck] = *(const bf16x8*)(Kt + krow + ((((ck << 2) + quad) ^ l16) << 3));
            f32x4 a0 = {0.f, 0.f, 0.f, 0.f}, a1 = {0.f, 0.f, 0.f, 0.f};
            #pragma unroll
            for (int ck = 0; ck < 4; ++ck) {
                a0 = __builtin_amdgcn_mfma_f32_16x16x32_bf16(kf[ck], qf[0][ck], a0, 0, 0, 0);
                a1 = __builtin_amdgcn_mfma_f32_16x16x32_bf16(kf[ck], qf[1][ck], a1, 0, 0, 0);
            }
            // raw v_exp_f32: valid since |arg| < ~95 << 128; <-126 flushes to 0 (wanted)
            f32x4 e0, e1;
            #pragma unroll
            for (int r = 0; r < 4; ++r) {
                e0[r] = __builtin_amdgcn_exp2f(a0[r]);
                e1[r] = __builtin_amdgcn_exp2f(a1[r]);
            }
            lsum0 += (e0[0] + e0[1]) + (e0[2] + e0[3]);
            lsum1 += (e1[0] + e1[1]) + (e1[2] + e1[3]);
            u32x2 pk0, pk1;
            pk0[0] = __builtin_amdgcn_perm(fbits(e0[1]), fbits(e0[0]), 0x07060302u);
            pk0[1] = __builtin_amdgcn_perm(fbits(e0[3]), fbits(e0[2]), 0x07060302u);
            pk1[0] = __builtin_amdgcn_perm(fbits(e1[1]), fbits(e1[0]), 0x07060302u);
            pk1[1] = __builtin_amdgcn_perm(fbits(e1[3]), fbits(e1[2]), 0x07060302u);
            const int jc = (js << 4) + (quad << 2);
            *(u32x2*)(pAw + l16 * 72 + jc)        = pk0;
            *(u32x2*)(pAw + (16 + l16) * 72 + jc) = pk1;
        }
        // ---- O^T += V·P^T ----
        bf16x8 pf[2][2];
        #pragma unroll
        for (int half = 0; half < 2; ++half)
            #pragma unroll
            for (int kh = 0; kh < 2; ++kh)
                pf[half][kh] = *(const bf16x8*)(pAw + ((half << 4) + l16) * 72 +
                                                (kh << 5) + (quad << 3));
        #pragma unroll
        for (int s = 0; s < 8; ++s) {
            const int vrow = ((s << 4) + l16) << 6;
            const bf16x8 v0 = *(const bf16x8*)(Vt + vrow + ((quad ^ (l16 & 7)) << 3));
            const bf16x8 v1 = *(const bf16x8*)(Vt + vrow + (((4 + quad) ^ (l16 & 7)) << 3));
            Oacc[0][s] = __builtin_amdgcn_mfma_f32_16x16x32_bf16(v0, pf[0][0], Oacc[0][s], 0, 0, 0);
            Oacc[0][s] = __builtin_amdgcn_mfma_f32_16x16x32_bf16(v1, pf[0][1], Oacc[0][s], 0, 0, 0);
            Oacc[1][s] = __builtin_amdgcn_mfma_f32_16x16x32_bf16(v0, pf[1][0], Oacc[1][s], 0, 0, 0);
            Oacc[1][s] = __builtin_amdgcn_mfma_f32_16x16x32_bf16(v1, pf[1][1], Oacc[1][s], 0, 0, 0);
        }
    }

    float l0 = lsum0; l0 += __shfl_xor(l0, 16); l0 += __shfl_xor(l0, 32);
    float l1 = lsum1; l1 += __shfl_xor(l1, 16); l1 += __shfl_xor(l1, 32);

    if (NSL == 1) {
        const float rl0 = 1.f / l0, rl1 = 1.f / l1;
        #pragma unroll
        for (int s = 0; s < 8; ++s)
            #pragma unroll
            for (int r = 0; r < 4; ++r) {
                const int h = (s << 4) + (quad << 2) + r;
                Obuf[(((b << 7) + h) << 12) + iw + l16]      = f2bf(Oacc[0][s][r] * rl0);
                Obuf[(((b << 7) + h) << 12) + iw + 16 + l16] = f2bf(Oacc[1][s][r] * rl1);
            }
    } else {
        const int slb = (sl << 2) + b;
        if (quad == 0) {
            lpart[(slb << 12) + iw + l16]      = l0;
            lpart[(slb << 12) + iw + 16 + l16] = l1;
        }
        unsigned short* Ob = Opart + ((long)slb << 19);
        #pragma unroll
        for (int half = 0; half < 2; ++half)
            #pragma unroll
            for (int s = 0; s < 8; ++s)
                #pragma unroll
                for (int r = 0; r < 4; ++r) {
                    const int h = (s << 4) + (quad << 2) + r;
                    Ob[(h << 12) + iw + (half << 4) + l16] = f2bf(Oacc[half][s][r]);
                }
    }
}

// ---------------- merge + BN stats + final, one block per channel ----------------
template<int NSL>
__global__ __launch_bounds__(1024) void mf_kernel(
    const unsigned short* __restrict__ Opart, const float* __restrict__ lpart,
    const float* __restrict__ x, const float* __restrict__ bnw,
    const float* __restrict__ bnb, const float* __restrict__ gammap,
    float* __restrict__ out)
{
    const int h = blockIdx.x;
    const int t = threadIdx.x;
    const int b = t >> 8;
    const int i0 = (t & 255) << 4;

    float A[16], L[16];
    #pragma unroll
    for (int k = 0; k < 16; ++k) { A[k] = 0.f; L[k] = 0.f; }
    #pragma unroll
    for (int sl = 0; sl < NSL; ++sl) {
        const int slb = (sl << 2) + b;
        const u16x8 u0 = *(const u16x8*)(Opart + ((long)slb << 19) + ((long)h << 12) + i0);
        const u16x8 u1 = *(const u16x8*)(Opart + ((long)slb << 19) + ((long)h << 12) + i0 + 8);
        const float* lp = lpart + (slb << 12) + i0;
        #pragma unroll
        for (int k = 0; k < 8; ++k) { A[k] += bf2f(u0[k]); A[8 + k] += bf2f(u1[k]); }
        #pragma unroll
        for (int k = 0; k < 4; ++k) {
            const float4 lv = *(const float4*)(lp + (k << 2));
            L[(k << 2) + 0] += lv.x; L[(k << 2) + 1] += lv.y;
            L[(k << 2) + 2] += lv.z; L[(k << 2) + 3] += lv.w;
        }
    }
    float o[16], s = 0.f, ss = 0.f;
    #pragma unroll
    for (int k = 0; k < 16; ++k) {
        o[k] = A[k] / L[k];
        s += o[k]; ss += o[k] * o[k];
    }
    #pragma unroll
    for (int off = 32; off; off >>= 1) {
        s  += __shfl_down(s, off);
        ss += __shfl_down(ss, off);
    }
    __shared__ float rs[16], rss[16], fin[2];
    const int wid = t >> 6;
    if ((t & 63) == 0) { rs[wid] = s; rss[wid] = ss; }
    __syncthreads();
    if (t == 0) {
        float s2 = 0.f, ss2 = 0.f;
        #pragma unroll
        for (int k = 0; k < 16; ++k) { s2 += rs[k]; ss2 += rss[k]; }
        fin[0] = s2; fin[1] = ss2;
    }
    __syncthreads();
    const float inv = 1.f / 16384.f;
    const float mean = fin[0] * inv;
    const float var  = fin[1] * inv - mean * mean;
    const float g = gammap[0];
    const float scale = bnw[h] * rsqrtf(var + EPSV);
    const float a  = g * scale;
    const float bb = g * (bnb[h] - mean * scale);

    const float* xp = x + (((b << 7) + h) << 12) + i0;
    float* op = out + (((b << 7) + h) << 12) + i0;
    #pragma unroll
    for (int k = 0; k < 4; ++k) {
        const float4 xv = *(const float4*)(xp + (k << 2));
        float4 r;
        r.x = o[(k << 2) + 0] * a + bb + xv.x;
        r.y = o[(k << 2) + 1] * a + bb + xv.y;
        r.z = o[(k << 2) + 2] * a + bb + xv.z;
        r.w = o[(k << 2) + 3] * a + bb + xv.w;
        *(float4*)(op + (k << 2)) = r;
    }
}

// NSL==1 variant: Obuf already normalized bf16
__global__ __launch_bounds__(1024) void mf1_kernel(
    const unsigned short* __restrict__ Obuf,
    const float* __restrict__ x, const float* __restrict__ bnw,
    const float* __restrict__ bnb, const float* __restrict__ gammap,
    float* __restrict__ out)
{
    const int h = blockIdx.x;
    const int t = threadIdx.x;
    const int b = t >> 8;
    const int i0 = (t & 255) << 4;
    const u16x8 u0 = *(const u16x8*)(Obuf + (((b << 7) + h) << 12) + i0);
    const u16x8 u1 = *(const u16x8*)(Obuf + (((b << 7) + h) << 12) + i0 + 8);
    float o[16], s = 0.f, ss = 0.f;
    #pragma unroll
    for (int k = 0; k < 8; ++k) { o[k] = bf2f(u0[k]); o[8 + k] = bf2f(u1[k]); }
    #pragma unroll
    for (int k = 0; k < 16; ++k) { s += o[k]; ss += o[k] * o[k]; }
    #pragma unroll
    for (int off = 32; off; off >>= 1) {
        s  += __shfl_down(s, off);
        ss += __shfl_down(ss, off);
    }
    __shared__ float rs[16], rss[16], fin[2];
    const int wid = t >> 6;
    if ((t & 63) == 0) { rs[wid] = s; rss[wid] = ss; }
    __syncthreads();
    if (t == 0) {
        float s2 = 0.f, ss2 = 0.f;
        #pragma unroll
        for (int k = 0; k < 16; ++k) { s2 += rs[k]; ss2 += rss[k]; }
        fin[0] = s2; fin[1] = ss2;
    }
    __syncthreads();
    const float inv = 1.f / 16384.f;
    const float mean = fin[0] * inv;
    const float var  = fin[1] * inv - mean * mean;
    const float g = gammap[0];
    const float scale = bnw[h] * rsqrtf(var + EPSV);
    const float a  = g * scale;
    const float bb = g * (bnb[h] - mean * scale);
    const float* xp = x + (((b << 7) + h) << 12) + i0;
    float* op = out + (((b << 7) + h) << 12) + i0;
    #pragma unroll
    for (int k = 0; k < 4; ++k) {
        const float4 xv = *(const float4*)(xp + (k << 2));
        float4 r;
        r.x = o[(k << 2) + 0] * a + bb + xv.x;
        r.y = o[(k << 2) + 1] * a + bb + xv.y;
        r.z = o[(k << 2) + 2] * a + bb + xv.z;
        r.w = o[(k << 2) + 3] * a + bb + xv.w;
        *(float4*)(op + (k << 2)) = r;
    }
}

extern "C" void kernel_launch(void* const* d_in, const int* in_sizes, int n_in,
                              void* d_out, int out_size, void* d_ws, size_t ws_size,
                              hipStream_t stream) {
    const float* x   = (const float*)d_in[0];
    const float* Wq  = (const float*)d_in[1];
    const float* bq  = (const float*)d_in[2];
    const float* Wk  = (const float*)d_in[3];
    const float* bk  = (const float*)d_in[4];
    const float* Wv  = (const float*)d_in[5];
    const float* bv  = (const float*)d_in[6];
    const float* bnw = (const float*)d_in[7];
    const float* bnb = (const float*)d_in[8];
    const float* gam = (const float*)d_in[9];
    float* out = (float*)d_out;

    char* ws = (char*)d_ws;
    unsigned short* Obuf = (unsigned short*)(ws);
    unsigned short* Qb   = (unsigned short*)(ws + (4u  << 20));
    unsigned short* Kb   = (unsigned short*)(ws + (8u  << 20));
    unsigned short* Vb   = (unsigned short*)(ws + (12u << 20));
    float*          lpart = (float*)(ws + (16u << 20) + (128u << 10));
    unsigned short* Opart = (unsigned short*)(ws + (17u << 20));

    int nsl = 1;
    if      (ws_size >= (17ull << 20) + (32ull << 20)) nsl = 8;
    else if (ws_size >= (17ull << 20) + (16ull << 20)) nsl = 4;
    else if (ws_size >= (17ull << 20) + (8ull  << 20)) nsl = 2;

    projx_kernel<<<768, 256, 0, stream>>>(x, Wq, Wk, Wv, bq, bk, bv, Qb, Kb, Vb);
    if (nsl == 8) {
        flash_kernel<8><<<1024, 256, 0, stream>>>(Qb, Kb, Vb, Opart, lpart, Obuf);
        mf_kernel<8><<<128, 1024, 0, stream>>>(Opart, lpart, x, bnw, bnb, gam, out);
    } else if (nsl == 4) {
        flash_kernel<4><<<512, 256, 0, stream>>>(Qb, Kb, Vb, Opart, lpart, Obuf);
        mf_kernel<4><<<128, 1024, 0, stream>>>(Opart, lpart, x, bnw, bnb, gam, out);
    } else if (nsl == 2) {
        flash_kernel<2><<<256, 256, 0, stream>>>(Qb, Kb, Vb, Opart, lpart, Obuf);
        mf_kernel<2><<<128, 1024, 0, stream>>>(Opart, lpart, x, bnw, bnb, gam, out);
    } else {
        flash_kernel<1><<<128, 256, 0, stream>>>(Qb, Kb, Vb, Opart, lpart, Obuf);
        mf1_kernel<<<128, 1024, 0, stream>>>(Obuf, x, bnw, bnb, gam, out);
    }
}